// Round 4
// baseline (313.042 us; speedup 1.0000x reference)
//
#include <hip/hip_runtime.h>

#define BATCH 131072
#define UNITS 512
#define DIM   64
#define BM    128     // rows per tile
#define TILES 2       // row-tiles per block -> grid 512 = exactly 2 blocks/CU
#define NFRAG 4096    // 8 gu * 4 t * 2 h * 64 lanes, 16B each = 64 KB

typedef __attribute__((ext_vector_type(8))) short  short8;
typedef __attribute__((ext_vector_type(4))) float  floatx4;

static __device__ __forceinline__ unsigned short f32_to_bf16(float f) {
    union { float f; unsigned int u; } c; c.f = f;
    unsigned int u = c.u;
    unsigned int r = u + 0x7fffu + ((u >> 16) & 1u);   // round-nearest-even
    return (unsigned short)(r >> 16);
}

// ---- per-row sum of squares of w ----
__global__ __launch_bounds__(256) void prep_wsq_kernel(
    const float* __restrict__ w, float* __restrict__ wsq)
{
    const int u = blockIdx.x * 4 + (threadIdx.x >> 6);   // one wave per w-row
    const int d = threadIdx.x & 63;
    float v = w[u * DIM + d];
    float s = v * v;
    #pragma unroll
    for (int o = 32; o > 0; o >>= 1) s += __shfl_xor(s, o);
    if (d == 0) wsq[u] = s;
}

// ---- pre-permute w into the MFMA B-fragment-linear bf16 image ----
// frag id fi = (g*4 + t)*2 + h; slot = fi*64 + lane (16 B each).
// Contents: row u = g*64 + t*16 + (lane&15), k = h*32 + (lane>>4)*8 .. +8.
// This is exactly bp[quad] / bp[quad+4] of the R1-verified layout, so the
// dist kernel reads each fragment as ONE linear ds_read_b128 (64 lanes ->
// 64 consecutive 16B slots: conflict-free).
__global__ __launch_bounds__(256) void prep_wfrag_kernel(
    const float* __restrict__ w, uint4* __restrict__ wbf)
{
    const int tid  = blockIdx.x * 256 + threadIdx.x;     // 16 blocks -> 4096
    const int lane = tid & 63;
    const int fi   = tid >> 6;
    const int h    = fi & 1;
    const int tt   = fi >> 1;                            // g*4 + t
    const int u    = (tt >> 2) * 64 + (tt & 3) * 16 + (lane & 15);
    const int k0   = h * 32 + (lane >> 4) * 8;
    const float* src = w + u * DIM + k0;
    float v[8];
    *(float4*)&v[0] = *(const float4*)src;
    *(float4*)&v[4] = *(const float4*)(src + 4);
    unsigned short p[8];
    #pragma unroll
    for (int i = 0; i < 8; ++i) p[i] = f32_to_bf16(v[i]);
    wbf[tid] = *(uint4*)p;
}

// dist[b,u] = ||x_b||^2 + ||w_u||^2 - 2 * x_b . w_u
//
// ZERO vmem loads in the main loop. Theory: vmcnt is FIFO, so the per-gu
// global B-loads of R0-R3 forced every MFMA's vmcnt wait to first retire
// ALL previously-issued output stores -> the store pipeline drained 16x per
// block and never streamed (the rocclr fill, with no loads, streams at
// 6.5 TB/s at 10% occupancy). Here: B comes from LDS (lgkmcnt — separate
// counter, no store interaction), x-fragments for both tiles are preloaded
// into registers, wsq is in LDS. Between the prologue barrier and kernel
// end the only vmem ops are stores -> they pipeline to full depth.
__global__ __launch_bounds__(256, 2) void dist_kernel(
    const float* __restrict__ x,
    const uint4* __restrict__ wbf,
    const float* __restrict__ wsq,
    float* __restrict__ out)
{
    __shared__ __align__(16) uint4 wbs[NFRAG];     // 64 KB
    __shared__ __align__(16) float wsq_s[UNITS];   // 2 KB  -> 66 KB: 2 blocks/CU

    const int tid  = threadIdx.x;
    const int wave = tid >> 6;
    const int lane = tid & 63;
    const int l15  = lane & 15;
    const int quad = lane >> 4;
    const int mrow = wave * 32;
    const int row0 = blockIdx.x * (BM * TILES);

    // ---- stage the (block-invariant) 64 KB fragment image + wsq ----
    #pragma unroll 4
    for (int i = 0; i < 16; ++i)
        wbs[i * 256 + tid] = wbf[i * 256 + tid];
    wsq_s[tid]       = wsq[tid];
    wsq_s[tid + 256] = wsq[tid + 256];

    // ---- preload x fragments for BOTH tiles (R1-verified swapped layout:
    //      frag row = l15, k = quad*8+j; xs2 = ||x_row(l15)||^2) ----
    short8 a[TILES][2][2];
    float  xs2[TILES][2];
    #pragma unroll
    for (int tl = 0; tl < TILES; ++tl) {
        #pragma unroll
        for (int mf = 0; mf < 2; ++mf) {
            const float* xr = x + (size_t)(row0 + tl * BM + mrow + mf * 16 + l15) * DIM;
            float v[16];
            *(float4*)&v[0]  = *(const float4*)(xr + quad * 8);
            *(float4*)&v[4]  = *(const float4*)(xr + quad * 8 + 4);
            *(float4*)&v[8]  = *(const float4*)(xr + 32 + quad * 8);
            *(float4*)&v[12] = *(const float4*)(xr + 32 + quad * 8 + 4);
            float s = 0.f;
            unsigned short p[16];
            #pragma unroll
            for (int i = 0; i < 16; ++i) { s += v[i] * v[i]; p[i] = f32_to_bf16(v[i]); }
            a[tl][mf][0] = *(short8*)&p[0];
            a[tl][mf][1] = *(short8*)&p[8];
            // the 4 lanes sharing l15 jointly hold all 64 elems of row l15
            s += __shfl_xor(s, 16);
            s += __shfl_xor(s, 32);
            xs2[tl][mf] = s;
        }
    }
    __syncthreads();                               // wbs + wsq_s ready

    // ---- main loop: ds_read + MFMA + VALU + stores only ----
    #pragma unroll
    for (int tl = 0; tl < TILES; ++tl) {
        for (int gu = 0; gu < 8; ++gu) {
            const int colb = gu * 64;

            short8  b[4][2];
            floatx4 wq[4];
            #pragma unroll
            for (int t = 0; t < 4; ++t) {
                const int fb = ((gu * 4 + t) * 2) * 64 + lane;
                uint4 r0 = wbs[fb];
                uint4 r1 = wbs[fb + 64];
                b[t][0] = *(short8*)&r0;
                b[t][1] = *(short8*)&r1;
                wq[t]   = *(const floatx4*)&wsq_s[colb + t * 16 + quad * 4];
            }

            #pragma unroll
            for (int mf = 0; mf < 2; ++mf) {
                #pragma unroll
                for (int t = 0; t < 4; ++t) {
                    floatx4 acc = floatx4{0.f, 0.f, 0.f, 0.f};
                    // swapped operands -> lane(quad,l15) holds
                    // D[u = colb+t*16+quad*4+i][row = l15]
                    acc = __builtin_amdgcn_mfma_f32_16x16x32_bf16(b[t][0], a[tl][mf][0], acc, 0, 0, 0);
                    acc = __builtin_amdgcn_mfma_f32_16x16x32_bf16(b[t][1], a[tl][mf][1], acc, 0, 0, 0);

                    floatx4 vo;
                    #pragma unroll
                    for (int i = 0; i < 4; ++i)
                        vo[i] = xs2[tl][mf] + wq[t][i] - 2.0f * acc[i];

                    float* dst = out + (size_t)(row0 + tl * BM + mrow + mf * 16 + l15) * UNITS
                                     + colb + t * 16 + quad * 4;
                    *(floatx4*)dst = vo;
                }
            }
        }
    }
}

extern "C" void kernel_launch(void* const* d_in, const int* in_sizes, int n_in,
                              void* d_out, int out_size, void* d_ws, size_t ws_size,
                              hipStream_t stream) {
    const float* x = (const float*)d_in[0];
    const float* w = (const float*)d_in[1];
    float* out = (float*)d_out;

    uint4* wbf = (uint4*)d_ws;                                  // 64 KB frag image
    float* wsq = (float*)((char*)d_ws + NFRAG * sizeof(uint4)); // 2 KB

    prep_wsq_kernel<<<UNITS / 4, 256, 0, stream>>>(w, wsq);
    prep_wfrag_kernel<<<NFRAG / 256, 256, 0, stream>>>(w, wbf);
    dist_kernel<<<BATCH / (BM * TILES), 256, 0, stream>>>(x, wbf, wsq, out);
}

// Round 5
// 298.074 us; speedup vs baseline: 1.0502x; 1.0502x over previous
//
#include <hip/hip_runtime.h>

#define BATCH 131072
#define UNITS 512
#define DIM   64
#define BROWS 256     // rows per block: 8 waves x 32 rows
#define NFRAG 4096    // 8 gu * 4 t * 2 h * 64 lanes, 16B each = 64 KB
#define STRIDE 68     // st row stride (floats)

typedef __attribute__((ext_vector_type(8))) short  short8;
typedef __attribute__((ext_vector_type(4))) float  floatx4;

static __device__ __forceinline__ unsigned short f32_to_bf16(float f) {
    union { float f; unsigned int u; } c; c.f = f;
    unsigned int u = c.u;
    unsigned int r = u + 0x7fffu + ((u >> 16) & 1u);   // round-nearest-even
    return (unsigned short)(r >> 16);
}

// ---- per-row sum of squares of w ----
__global__ __launch_bounds__(256) void prep_wsq_kernel(
    const float* __restrict__ w, float* __restrict__ wsq)
{
    const int u = blockIdx.x * 4 + (threadIdx.x >> 6);
    const int d = threadIdx.x & 63;
    float v = w[u * DIM + d];
    float s = v * v;
    #pragma unroll
    for (int o = 32; o > 0; o >>= 1) s += __shfl_xor(s, o);
    if (d == 0) wsq[u] = s;
}

// ---- pre-permute w into the MFMA B-fragment-linear bf16 image ----
// frag fi = (g*4 + t)*2 + h; slot = fi*64 + lane (16 B each):
// row u = g*64 + t*16 + (lane&15), k = h*32 + (lane>>4)*8 .. +8.
__global__ __launch_bounds__(256) void prep_wfrag_kernel(
    const float* __restrict__ w, uint4* __restrict__ wbf)
{
    const int tid  = blockIdx.x * 256 + threadIdx.x;
    const int lane = tid & 63;
    const int fi   = tid >> 6;
    const int h    = fi & 1;
    const int tt   = fi >> 1;
    const int u    = (tt >> 2) * 64 + (tt & 3) * 16 + (lane & 15);
    const int k0   = h * 32 + (lane >> 4) * 8;
    const float* src = w + u * DIM + k0;
    float v[8];
    *(float4*)&v[0] = *(const float4*)src;
    *(float4*)&v[4] = *(const float4*)(src + 4);
    unsigned short p[8];
    #pragma unroll
    for (int i = 0; i < 8; ++i) p[i] = f32_to_bf16(v[i]);
    wbf[tid] = *(uint4*)p;
}

// dist[b,u] = ||x_b||^2 + ||w_u||^2 - 2 * x_b . w_u
//
// FACTORIAL COMPLETION. Measured (clock-normalized vs same-run fill BW):
//   loads-in-loop + 256B store segments : ~129 us   (R0/R3)
//   loads-in-loop +  64B store segments : ~160 us   (R1)
//   no-loads      +  64B store segments :  ~99 us   (R4)
//   no-loads      + 256B store segments :  THIS KERNEL
// Theory: vmcnt is FIFO, so in-loop vmem loads force stores to retire
// before every MFMA (fixed in R4); AND narrow 64B segments quadruple the
// per-byte L2 write-request rate vs full-line 256B segments. R1 vs R2
// "segments don't matter" was measured in the loads-in-loop regime where
// the pipeline never got deep enough for width to show. Here: R4's loop
// (B via ds_read_b128 from LDS frag image, x preloaded in regs, ZERO vmem
// loads after the prologue barrier) + R0's verified wave-private LDS
// transpose epilogue (every store = 4 x 256B full-line segments, within a
// 32-row window per wave). Occupancy held at 8 waves/CU (1 block x 512T,
// 100 KB LDS) so segment width is the only changed variable vs R4.
__global__ __launch_bounds__(512, 2) void dist_kernel(
    const float* __restrict__ x,
    const uint4* __restrict__ wbf,
    const float* __restrict__ wsq,
    float* __restrict__ out)
{
    __shared__ __align__(16) uint4 wbs[NFRAG];            // 64 KB
    __shared__ __align__(16) float wsq_s[UNITS];          // 2 KB
    __shared__ __align__(16) float st[8][16][STRIDE];     // 34 KB -> 100 KB total

    const int tid  = threadIdx.x;
    const int wave = tid >> 6;
    const int lane = tid & 63;
    const int l15  = lane & 15;
    const int quad = lane >> 4;
    const int mrow = wave * 32;
    const int row0 = blockIdx.x * BROWS;

    // ---- stage block-invariant fragment image + wsq ----
    #pragma unroll
    for (int i = 0; i < 8; ++i)
        wbs[i * 512 + tid] = wbf[i * 512 + tid];
    wsq_s[tid] = wsq[tid];

    // ---- preload x fragments to registers (verified layout:
    //      A[m = l15][k = quad*8 + j], halves k<32 / k>=32) ----
    short8 a[2][2];
    float  xs[2][4];
    #pragma unroll
    for (int mf = 0; mf < 2; ++mf) {
        const float* xr = x + (size_t)(row0 + mrow + mf * 16 + l15) * DIM;
        float v[16];
        *(float4*)&v[0]  = *(const float4*)(xr + quad * 8);
        *(float4*)&v[4]  = *(const float4*)(xr + quad * 8 + 4);
        *(float4*)&v[8]  = *(const float4*)(xr + 32 + quad * 8);
        *(float4*)&v[12] = *(const float4*)(xr + 32 + quad * 8 + 4);
        float s = 0.f;
        unsigned short p[16];
        #pragma unroll
        for (int i = 0; i < 16; ++i) { s += v[i] * v[i]; p[i] = f32_to_bf16(v[i]); }
        a[mf][0] = *(short8*)&p[0];
        a[mf][1] = *(short8*)&p[8];
        s += __shfl_xor(s, 16);
        s += __shfl_xor(s, 32);          // s = ||x_row(mrow+mf*16+l15)||^2, lanes 0-15 hold rows 0-15
        #pragma unroll
        for (int i = 0; i < 4; ++i)
            xs[mf][i] = __shfl(s, quad * 4 + i);   // row this lane's acc[i] covers
    }
    __syncthreads();                     // wbs + wsq_s ready; no vmem loads after this

    float* stw = &st[wave][0][0];        // wave-private transpose stage

    for (int gu = 0; gu < 8; ++gu) {
        const int colb = gu * 64;

        // B-frags: one linear ds_read_b128 each (64 lanes -> 64 consecutive 16B slots)
        short8 b[4][2];
        float  wq[4];
        #pragma unroll
        for (int t = 0; t < 4; ++t) {
            const int fb = ((gu * 4 + t) * 2) * 64 + lane;
            uint4 r0 = wbs[fb];
            uint4 r1 = wbs[fb + 64];
            b[t][0] = *(short8*)&r0;
            b[t][1] = *(short8*)&r1;
            wq[t]   = wsq_s[colb + t * 16 + l15];
        }

        #pragma unroll
        for (int mf = 0; mf < 2; ++mf) {
            floatx4 acc[4];
            #pragma unroll
            for (int t = 0; t < 4; ++t) {
                acc[t] = floatx4{0.f, 0.f, 0.f, 0.f};
                acc[t] = __builtin_amdgcn_mfma_f32_16x16x32_bf16(a[mf][0], b[t][0], acc[t], 0, 0, 0);
                acc[t] = __builtin_amdgcn_mfma_f32_16x16x32_bf16(a[mf][1], b[t][1], acc[t], 0, 0, 0);
            }

            // C/D layout (verified): row = quad*4 + i, col = t*16 + l15
            #pragma unroll
            for (int t = 0; t < 4; ++t)
                #pragma unroll
                for (int i = 0; i < 4; ++i)
                    stw[(quad * 4 + i) * STRIDE + t * 16 + l15] =
                        xs[mf][i] + wq[t] - 2.0f * acc[t][i];

            // readback + stores: each instruction = 4 rows x 256B full-line
            // segments (wave-private LDS, DS in-order -> no barrier)
            #pragma unroll
            for (int j = 0; j < 4; ++j) {
                const int r = quad + 4 * j;
                const floatx4 v = *(const floatx4*)&stw[r * STRIDE + l15 * 4];
                float* dst = out + (size_t)(row0 + mrow + mf * 16 + r) * UNITS
                                 + colb + l15 * 4;
                *(floatx4*)dst = v;
            }
        }
    }
}

extern "C" void kernel_launch(void* const* d_in, const int* in_sizes, int n_in,
                              void* d_out, int out_size, void* d_ws, size_t ws_size,
                              hipStream_t stream) {
    const float* x = (const float*)d_in[0];
    const float* w = (const float*)d_in[1];
    float* out = (float*)d_out;

    uint4* wbf = (uint4*)d_ws;                                  // 64 KB frag image
    float* wsq = (float*)((char*)d_ws + NFRAG * sizeof(uint4)); // 2 KB

    prep_wsq_kernel<<<UNITS / 4, 256, 0, stream>>>(w, wsq);
    prep_wfrag_kernel<<<NFRAG / 256, 256, 0, stream>>>(w, wbf);
    dist_kernel<<<BATCH / BROWS, 512, 0, stream>>>(x, wbf, wsq, out);
}